// Round 12
// baseline (5828.202 us; speedup 1.0000x reference)
//
#include <hip/hip_runtime.h>

// AdaptiveDownsampling: farthest point sampling (B=8, N=8192, m=4096) + gather.
// Outputs concatenated flat: dp [8,4096,3] then df [8,4096,256], float32.
//
// r2: np reference computes in float64 -> exact path must be fp64.
// r6: fp32 screen + rare exact fp64 path (sound: nonneg, margin 1e-4).
// r7 (4239us, best): 2 barriers + atomics, thin parallel tail.
// r9/r10/r11 (5.0-5.2ms): avg-wave issue cuts didn't move the wall ->
//   model: wall = critical-wave work + handshake latency; barrier lockstep
//   makes non-critical-wave savings invisible.
// r12: shrink the handshake. BLOCK=512 (8 waves): per-SIMD screen issue
//   unchanged (2048 pts/SIMD), but 8 partials (3 lex stages), half the
//   barrier width, half the redundant-tail issue. Single-barrier ping-pong
//   pair scheme (r11), outer fp64 gate (r10), dirty skip (r9), ballot +
//   scalar-pipe owner scan (r10, extended to 16 slots), b128 coord fetch.
//   __launch_bounds__(512,1) -> 256 VGPR cap so fp64 state fits registers.

typedef float v2f __attribute__((ext_vector_type(2)));

#define BATCH 8
#define NPTS  8192
#define MSEL  4096
#define NFEAT 256
#define BLOCK 512
#define PPT   16       // points per thread = NPTS / BLOCK

// fp64 square, opaque to the compiler so no v_fma_f64 contraction can merge
// the following adds (numpy float64 does separate mul / add / add).
__device__ __forceinline__ double sqd(double x) {
    double r;
    asm("v_mul_f64 %0, %1, %1" : "=v"(r) : "v"(x));
    return r;
}

// Exact 64-lane u32 max, VALU-only DPP (r7-verified), broadcast via lane 63.
__device__ __forceinline__ unsigned wave_umax(unsigned v) {
    unsigned t;
    t = (unsigned)__builtin_amdgcn_update_dpp(0, (int)v, 0x111, 0xf, 0xf, false); v = v > t ? v : t; // row_shr:1
    t = (unsigned)__builtin_amdgcn_update_dpp(0, (int)v, 0x112, 0xf, 0xf, false); v = v > t ? v : t; // row_shr:2
    t = (unsigned)__builtin_amdgcn_update_dpp(0, (int)v, 0x114, 0xf, 0xf, false); v = v > t ? v : t; // row_shr:4
    t = (unsigned)__builtin_amdgcn_update_dpp(0, (int)v, 0x118, 0xf, 0xf, false); v = v > t ? v : t; // row_shr:8
    t = (unsigned)__builtin_amdgcn_update_dpp(0, (int)v, 0x142, 0xf, 0xf, false); v = v > t ? v : t; // row_bcast:15
    t = (unsigned)__builtin_amdgcn_update_dpp(0, (int)v, 0x143, 0xf, 0xf, false); v = v > t ? v : t; // row_bcast:31
    return (unsigned)__builtin_amdgcn_readlane((int)v, 63);
}

// One lex-reduce stage over rows of 16 (r9/r11-verified): take neighbor if
// value greater, or equal with smaller index. Invalid lanes inject
// (0,0,0xffffffff) which loses to any real entry. CTRL must be an ICE.
template <int CTRL>
__device__ __forceinline__ void lex_stage(unsigned& hi, unsigned& lo, unsigned& idx) {
    const unsigned ohi  = (unsigned)__builtin_amdgcn_update_dpp(0,  (int)hi,  CTRL, 0xf, 0xf, false);
    const unsigned olo  = (unsigned)__builtin_amdgcn_update_dpp(0,  (int)lo,  CTRL, 0xf, 0xf, false);
    const unsigned oidx = (unsigned)__builtin_amdgcn_update_dpp(-1, (int)idx, CTRL, 0xf, 0xf, false);
    const bool take = (ohi > hi) || (ohi == hi && ((olo > lo) || (olo == lo && oidx < idx)));
    hi  = take ? ohi  : hi;
    lo  = take ? olo  : lo;
    idx = take ? oidx : idx;
}

__launch_bounds__(BLOCK, 1)
__global__ void fps_kernel(const float* __restrict__ pts,   // [B, N, 3]
                           float* __restrict__ dp,          // [B, M, 3]
                           int* __restrict__ idx_out)       // [B, M]
{
    __shared__ float4 s_pts4[NPTS];       // 128 KB {x,y,z,-}: 1-trip winner fetch
    __shared__ ulonglong2 s_pair[2][8];   // per-wave {max_bits, first_idx}, ping-pong

    const int b   = blockIdx.x;
    const int tid = threadIdx.x;
    const float* p = pts + (size_t)b * NPTS * 3;

    for (int i = tid; i < NPTS; i += BLOCK)
        s_pts4[i] = (float4){p[i * 3 + 0], p[i * 3 + 1], p[i * 3 + 2], 0.0f};

    // 16 points/thread as 8 float2 pairs (slots 2P, 2P+1); point n = tid + j*512.
#define DECLP(P, J0, J1) \
    v2f pxp##P = { p[(tid + J0 * 512) * 3 + 0], p[(tid + J1 * 512) * 3 + 0] }; \
    v2f pyp##P = { p[(tid + J0 * 512) * 3 + 1], p[(tid + J1 * 512) * 3 + 1] }; \
    v2f pzp##P = { p[(tid + J0 * 512) * 3 + 2], p[(tid + J1 * 512) * 3 + 2] };
    DECLP(0, 0, 1)  DECLP(1, 2, 3)  DECLP(2, 4, 5)  DECLP(3, 6, 7)
    DECLP(4, 8, 9)  DECLP(5, 10, 11) DECLP(6, 12, 13) DECLP(7, 14, 15)
#undef DECLP
    double mind0 = 1e10, mind1 = 1e10, mind2 = 1e10, mind3 = 1e10;
    double mind4 = 1e10, mind5 = 1e10, mind6 = 1e10, mind7 = 1e10;
    double mind8 = 1e10, mind9 = 1e10, mind10 = 1e10, mind11 = 1e10;
    double mind12 = 1e10, mind13 = 1e10, mind14 = 1e10, mind15 = 1e10;
    v2f mfmp0 = {1.0001e10f, 1.0001e10f}, mfmp1 = {1.0001e10f, 1.0001e10f};
    v2f mfmp2 = {1.0001e10f, 1.0001e10f}, mfmp3 = {1.0001e10f, 1.0001e10f};
    v2f mfmp4 = {1.0001e10f, 1.0001e10f}, mfmp5 = {1.0001e10f, 1.0001e10f};
    v2f mfmp6 = {1.0001e10f, 1.0001e10f}, mfmp7 = {1.0001e10f, 1.0001e10f};

    // Selection 0 is point 0 (deterministic start).
    float cx = p[0], cy = p[1], cz = p[2];
    if (tid == 0) {
        dp[(size_t)b * MSEL * 3 + 0] = cx;
        dp[(size_t)b * MSEL * 3 + 1] = cy;
        dp[(size_t)b * MSEL * 3 + 2] = cz;
        idx_out[b * MSEL + 0] = 0;
    }

    const int lane = tid & 63;
    const int wid  = tid >> 6;

    // Per-wave cached reduction result; every wave is dirty at k=1 (inits
    // s_pair[1] before first read; k=2 writes cached values into s_pair[0]).
    // Single-barrier ping-pong race-freedom: a wave writes buffer (k+1)&1
    // only after passing iter k's barrier, which orders it after all reads
    // of that buffer from iter k-1.
    unsigned long long wbits = 0ull;
    unsigned           widxw = 0xffffffffu;

    __syncthreads();   // s_pts4 visible

    for (int k = 1; k < MSEL; ++k) {
        const double cxd = (double)cx, cyd = (double)cy, czd = (double)cz;
        const v2f cx2 = {cx, cx}, cy2 = {cy, cy}, cz2 = {cz, cz};
        bool upd = false;

        // --- packed fp32 screen: distances for all 16 slots ---
        v2f d0, d1, d2, d3, d4, d5, d6, d7;
#define SCREEN(P) { \
        const v2f dx = pxp##P - cx2, dy = pyp##P - cy2, dz = pzp##P - cz2; \
        d##P = dx * dx + dy * dy + dz * dz; }
        SCREEN(0) SCREEN(1) SCREEN(2) SCREEN(3)
        SCREEN(4) SCREEN(5) SCREEN(6) SCREEN(7)
#undef SCREEN
        float mn;
        {   // slack dies in this scope (r10 spill lesson)
            const v2f e0 = d0 - mfmp0, e1 = d1 - mfmp1;
            const v2f e2 = d2 - mfmp2, e3 = d3 - mfmp3;
            const v2f e4 = d4 - mfmp4, e5 = d5 - mfmp5;
            const v2f e6 = d6 - mfmp6, e7 = d7 - mfmp7;
            const float m0 = fminf(fminf(e0.x, e0.y), fminf(e1.x, e1.y));
            const float m1 = fminf(fminf(e2.x, e2.y), fminf(e3.x, e3.y));
            const float m2 = fminf(fminf(e4.x, e4.y), fminf(e5.x, e5.y));
            const float m3 = fminf(fminf(e6.x, e6.y), fminf(e7.x, e7.y));
            mn = fminf(fminf(m0, m1), fminf(m2, m3));
        }

        // --- wave-uniform gate around all fp64 trigger blocks (r10) ---
        if (__ballot(mn < 0.0f) != 0ull) {
#define EX64(PX, PY, PZ, MD, MF) { \
            const double ddx = (double)(PX) - cxd; \
            const double ddy = (double)(PY) - cyd; \
            const double ddz = (double)(PZ) - czd; \
            const double dd  = (sqd(ddx) + sqd(ddy)) + sqd(ddz); \
            if (dd < MD) { MD = dd; MF = (float)dd * 1.0001f; upd = true; } }
#define TRIG(P, J0, J1) \
            if (d##P.x < mfmp##P.x) EX64(pxp##P.x, pyp##P.x, pzp##P.x, mind##J0, mfmp##P.x) \
            if (d##P.y < mfmp##P.y) EX64(pxp##P.y, pyp##P.y, pzp##P.y, mind##J1, mfmp##P.y)
            TRIG(0, 0, 1)   TRIG(1, 2, 3)   TRIG(2, 4, 5)   TRIG(3, 6, 7)
            TRIG(4, 8, 9)   TRIG(5, 10, 11) TRIG(6, 12, 13) TRIG(7, 14, 15)
#undef TRIG
#undef EX64
        }

        // --- per-wave reduce, only if some lane updated (winner's wave is
        //     always dirty since its mind -> ~0, so the skip is safe) ---
        if (__ballot(upd) != 0ull) {
            const double a0 = fmax(fmax(mind0, mind1),  fmax(mind2, mind3));
            const double a1 = fmax(fmax(mind4, mind5),  fmax(mind6, mind7));
            const double a2 = fmax(fmax(mind8, mind9),  fmax(mind10, mind11));
            const double a3 = fmax(fmax(mind12, mind13), fmax(mind14, mind15));
            const double tbv = fmax(fmax(a0, a1), fmax(a2, a3));

            // wave max of nonneg double bits: two u32 DPP passes (exact)
            const unsigned long long tb = (unsigned long long)__double_as_longlong(tbv);
            const unsigned thi  = (unsigned)(tb >> 32);
            const unsigned hmax = wave_umax(thi);
            const unsigned lmax = wave_umax((thi == hmax) ? (unsigned)tb : 0u);
            wbits = ((unsigned long long)hmax << 32) | (unsigned long long)lmax;

            // first-owner scan: 16 ballots + scalar-pipe cselects (r10-exact).
            // Global idx = j*512 + wid*64 + lane; j-stride dominates lane span,
            // so ascending j then ctz(ballot) = min global idx in this wave.
            const double wmax = __longlong_as_double((long long)wbits);
            const unsigned long long B0  = __ballot(mind0  == wmax);
            const unsigned long long B1  = __ballot(mind1  == wmax);
            const unsigned long long B2  = __ballot(mind2  == wmax);
            const unsigned long long B3  = __ballot(mind3  == wmax);
            const unsigned long long B4  = __ballot(mind4  == wmax);
            const unsigned long long B5  = __ballot(mind5  == wmax);
            const unsigned long long B6  = __ballot(mind6  == wmax);
            const unsigned long long B7  = __ballot(mind7  == wmax);
            const unsigned long long B8  = __ballot(mind8  == wmax);
            const unsigned long long B9  = __ballot(mind9  == wmax);
            const unsigned long long B10 = __ballot(mind10 == wmax);
            const unsigned long long B11 = __ballot(mind11 == wmax);
            const unsigned long long B12 = __ballot(mind12 == wmax);
            const unsigned long long B13 = __ballot(mind13 == wmax);
            const unsigned long long B14 = __ballot(mind14 == wmax);
            const unsigned long long B15 = __ballot(mind15 == wmax);
            unsigned long long bb = B15; unsigned jj = 15u;  // dirty wave => some owner
            if (B14) { bb = B14; jj = 14u; }
            if (B13) { bb = B13; jj = 13u; }
            if (B12) { bb = B12; jj = 12u; }
            if (B11) { bb = B11; jj = 11u; }
            if (B10) { bb = B10; jj = 10u; }
            if (B9)  { bb = B9;  jj = 9u;  }
            if (B8)  { bb = B8;  jj = 8u;  }
            if (B7)  { bb = B7;  jj = 7u;  }
            if (B6)  { bb = B6;  jj = 6u;  }
            if (B5)  { bb = B5;  jj = 5u;  }
            if (B4)  { bb = B4;  jj = 4u;  }
            if (B3)  { bb = B3;  jj = 3u;  }
            if (B2)  { bb = B2;  jj = 2u;  }
            if (B1)  { bb = B1;  jj = 1u;  }
            if (B0)  { bb = B0;  jj = 0u;  }
            widxw = (jj << 9) + (unsigned)(wid << 6) + (unsigned)__builtin_ctzll(bb);
        }
        if (lane == 0)
            s_pair[k & 1][wid] = (ulonglong2){wbits, (unsigned long long)widxw};
        __syncthreads();                                   // the ONLY barrier

        // --- all waves: lex reduce of 8 pairs (3 DPP stages, lanes 0-7) ---
        const ulonglong2 pe = s_pair[k & 1][lane & 7];
        unsigned hi  = (unsigned)(pe.x >> 32);
        unsigned lo  = (unsigned)pe.x;
        unsigned ix  = (unsigned)pe.y;
        lex_stage<0x111>(hi, lo, ix);   // row_shr:1
        lex_stage<0x112>(hi, lo, ix);   // row_shr:2
        lex_stage<0x114>(hi, lo, ix);   // row_shr:4 -> lane 7 complete
        const int widx = __builtin_amdgcn_readlane((int)ix, 7);

        // --- single b128 broadcast read of winner coords ---
        const float4 rc = s_pts4[widx];
        cx = rc.x; cy = rc.y; cz = rc.z;
        if (tid == 0) {
            idx_out[b * MSEL + k] = widx;
            float* o = dp + ((size_t)b * MSEL + k) * 3;
            o[0] = rc.x; o[1] = rc.y; o[2] = rc.z;
        }
    }
}

// One wave per selected row; lane i moves one float4 (64 * 16B = 1024B = full row).
__global__ void gather_kernel(const float* __restrict__ feats,  // [B, N, C]
                              const int* __restrict__ idx,      // [B, M]
                              float* __restrict__ df)           // [B, M, C]
{
    const int row  = blockIdx.x * 4 + (threadIdx.x >> 6);  // [0, B*M)
    const int lane = threadIdx.x & 63;
    const int b    = row >> 12;         // MSEL = 4096 rows per batch
    const int src  = idx[row];
    const float4* s = (const float4*)(feats + ((size_t)b * NPTS + src) * NFEAT);
    float4*       d = (float4*)(df + (size_t)row * NFEAT);
    d[lane] = s[lane];
}

extern "C" void kernel_launch(void* const* d_in, const int* in_sizes, int n_in,
                              void* d_out, int out_size, void* d_ws, size_t ws_size,
                              hipStream_t stream)
{
    const float* points   = (const float*)d_in[0];   // [8, 8192, 3]
    const float* features = (const float*)d_in[1];   // [8, 8192, 256]
    float* out = (float*)d_out;
    float* dp  = out;                                // [8, 4096, 3]
    float* df  = out + (size_t)BATCH * MSEL * 3;     // [8, 4096, 256]
    int*   idx_ws = (int*)d_ws;                      // [8, 4096] = 128 KB scratch

    fps_kernel<<<BATCH, BLOCK, 0, stream>>>(points, dp, idx_ws);
    gather_kernel<<<(BATCH * MSEL) / 4, 256, 0, stream>>>(features, idx_ws, df);
}